// Round 3
// baseline (304.301 us; speedup 1.0000x reference)
//
#include <hip/hip_runtime.h>

// VectorQuantizer: N=65536 rows, D=256, K=1024 codes, fp32 in/out.
// argmin_k ||x-e_k||^2 == argmax_k (x.e_k - 0.5*||e_k||^2).
// fp16 2-term split: x = xh + xl exactly (fp16 pair); e quantized to fp16 once
// (cnorm exact fp32). score ~= xh.eh + xl.eh; error = x.(e-eh), |err| <~ 0.04.
// Exact-fp32 rescue for rows with approx top-2 margin <= 0.1.

#define N_ROWS 65536
#define K_EMB  1024
#define D_DIM  256
#define BK     32

typedef unsigned long long u64;
typedef __attribute__((ext_vector_type(8)))  _Float16 f16x8;
typedef __attribute__((ext_vector_type(4)))  _Float16 f16x4;
typedef __attribute__((ext_vector_type(16))) float    f32x16;

__device__ __forceinline__ unsigned int f32_sortable(float f) {
    unsigned int u = __float_as_uint(f);
    return (u & 0x80000000u) ? ~u : (u | 0x80000000u);
}
__device__ __forceinline__ float f32_unsort(unsigned int u) {
    unsigned int v = (u & 0x80000000u) ? (u ^ 0x80000000u) : ~u;
    return __uint_as_float(v);
}

#define GLDS(gp, lp) __builtin_amdgcn_global_load_lds( \
    (const __attribute__((address_space(1))) void*)(gp), \
    (__attribute__((address_space(3))) void*)(lp), 16, 0, 0)

// ---- pass 0: split x into fp16 hi/lo (into d_out scratch); split e + cnorm ----
// blocks [0, 16384): x float4s.  blocks [16384, 16640): e rows + cnorm.
__global__ void vq_prep(const float* __restrict__ x, const float* __restrict__ emb,
                        _Float16* __restrict__ xhi, _Float16* __restrict__ xlo,
                        _Float16* __restrict__ ehi, float* __restrict__ cnorm) {
    int b = blockIdx.x, t = threadIdx.x;
    if (b < 16384) {
        int i = b * 256 + t;                     // float4 index
        float4 v = ((const float4*)x)[i];
        _Float16 h0 = (_Float16)v.x, h1 = (_Float16)v.y;
        _Float16 h2 = (_Float16)v.z, h3 = (_Float16)v.w;
        f16x4 hv = {h0, h1, h2, h3};
        f16x4 lv = {(_Float16)(v.x - (float)h0), (_Float16)(v.y - (float)h1),
                    (_Float16)(v.z - (float)h2), (_Float16)(v.w - (float)h3)};
        ((f16x4*)xhi)[i] = hv;
        ((f16x4*)xlo)[i] = lv;
    } else {
        int gid = (b - 16384) * 256 + t;
        int code = gid >> 6, lane = gid & 63;
        float4 v = ((const float4*)(emb + (size_t)code * D_DIM))[lane];
        f16x4 hv = {(_Float16)v.x, (_Float16)v.y, (_Float16)v.z, (_Float16)v.w};
        ((f16x4*)(ehi + (size_t)code * D_DIM))[lane] = hv;
        float s = v.x * v.x + v.y * v.y + v.z * v.z + v.w * v.w;
        #pragma unroll
        for (int off = 32; off > 0; off >>= 1) s += __shfl_down(s, off, 64);
        if (lane == 0) cnorm[code] = 0.5f * s;
    }
}

// ---- pass 1: fp16 2-term MFMA GEMM + fused per-row/col-block top-2 ----
// Block tile 128x128, BK=32, 4 waves (2x2), wave = 2x2 of 32x32x16 MFMA x2 terms.
// LDS layout per buffer: [k-quarter 0..3][row 0..127] 16B chunks -> GLDS dest is
// wave-uniform base + lane*16 (wave w stages k-quarter w), and fragment b128
// reads hit consecutive chunks (conflict-free).
__global__ __launch_bounds__(256, 2) void vq_gemm(
    const _Float16* __restrict__ xh, const _Float16* __restrict__ xl,
    const _Float16* __restrict__ eh, const float* __restrict__ cnorm,
    u64* __restrict__ top2)
{
    __shared__ _Float16 Ah[4 * 128 * 8];   // 8 KB each
    __shared__ _Float16 Al[4 * 128 * 8];
    __shared__ _Float16 Bh[4 * 128 * 8];

    const int t = threadIdx.x, w = t >> 6, lane = t & 63;
    const int wrow = w >> 1, wcol = w & 1;
    const int m = lane & 31, kh = lane >> 5;
    const int row0 = blockIdx.y * 128, col0 = blockIdx.x * 128;

    // staging: wave w owns k-quarter w; lane covers rows {lane, lane+64}
    const _Float16* gAh = xh + (size_t)(row0 + lane) * D_DIM + w * 8;
    const _Float16* gAl = xl + (size_t)(row0 + lane) * D_DIM + w * 8;
    const _Float16* gBh = eh + (size_t)(col0 + lane) * D_DIM + w * 8;
    _Float16* lAh = Ah + w * 1024;          // wave-uniform LDS bases (chunks)
    _Float16* lAl = Al + w * 1024;
    _Float16* lBh = Bh + w * 1024;

    // fragment chunk indices (in 16B units): chunk = kq*128 + row
    const int rA0 = wrow * 64 + m, rA1 = wrow * 64 + 32 + m;
    const int cB0 = wcol * 64 + m, cB1 = wcol * 64 + 32 + m;
    const f16x8* fAh = (const f16x8*)Ah;
    const f16x8* fAl = (const f16x8*)Al;
    const f16x8* fBh = (const f16x8*)Bh;

    f32x16 acc[2][2] = {};

    for (int kt = 0; kt < D_DIM; kt += BK) {
        GLDS(gAh, lAh); GLDS(gAh + 64 * D_DIM, lAh + 512);
        GLDS(gAl, lAl); GLDS(gAl + 64 * D_DIM, lAl + 512);
        GLDS(gBh, lBh); GLDS(gBh + 64 * D_DIM, lBh + 512);
        gAh += BK; gAl += BK; gBh += BK;
        __syncthreads();
        #pragma unroll
        for (int k2 = 0; k2 < 2; k2++) {
            const int kq = (2 * k2 + kh) * 128;
            f16x8 ah0 = fAh[kq + rA0], ah1 = fAh[kq + rA1];
            f16x8 al0 = fAl[kq + rA0], al1 = fAl[kq + rA1];
            f16x8 bh0 = fBh[kq + cB0], bh1 = fBh[kq + cB1];
            acc[0][0] = __builtin_amdgcn_mfma_f32_32x32x16_f16(ah0, bh0, acc[0][0], 0, 0, 0);
            acc[0][1] = __builtin_amdgcn_mfma_f32_32x32x16_f16(ah0, bh1, acc[0][1], 0, 0, 0);
            acc[1][0] = __builtin_amdgcn_mfma_f32_32x32x16_f16(ah1, bh0, acc[1][0], 0, 0, 0);
            acc[1][1] = __builtin_amdgcn_mfma_f32_32x32x16_f16(ah1, bh1, acc[1][1], 0, 0, 0);
            acc[0][0] = __builtin_amdgcn_mfma_f32_32x32x16_f16(al0, bh0, acc[0][0], 0, 0, 0);
            acc[0][1] = __builtin_amdgcn_mfma_f32_32x32x16_f16(al0, bh1, acc[0][1], 0, 0, 0);
            acc[1][0] = __builtin_amdgcn_mfma_f32_32x32x16_f16(al1, bh0, acc[1][0], 0, 0, 0);
            acc[1][1] = __builtin_amdgcn_mfma_f32_32x32x16_f16(al1, bh1, acc[1][1], 0, 0, 0);
        }
        __syncthreads();
    }

    // epilogue: per-row top2 over this wave's 64 cols via 32-lane shuffles,
    // then cross-wcol merge through a 4KB LDS scratch (reusing Ah).
    float cn0 = cnorm[col0 + wcol * 64 + m];
    float cn1 = cnorm[col0 + wcol * 64 + 32 + m];
    u64* scr = (u64*)Ah;   // 128 rows x {wcol0:b,b2, wcol1:b,b2}
    __syncthreads();       // all waves done with LDS tiles

    #pragma unroll
    for (int rt = 0; rt < 2; rt++) {
        #pragma unroll
        for (int reg = 0; reg < 16; reg++) {
            float s0 = acc[rt][0][reg] - cn0;
            float s1 = acc[rt][1][reg] - cn1;
            u64 p0 = ((u64)f32_sortable(s0) << 32) |
                     (u64)(unsigned int)(K_EMB - 1 - (col0 + wcol * 64 + m));
            u64 p1 = ((u64)f32_sortable(s1) << 32) |
                     (u64)(unsigned int)(K_EMB - 1 - (col0 + wcol * 64 + 32 + m));
            u64 b  = p0 > p1 ? p0 : p1;
            u64 b2 = p0 > p1 ? p1 : p0;
            #pragma unroll
            for (int d = 1; d < 32; d <<= 1) {
                u64 ob  = (u64)__shfl_xor((long long)b, d, 64);
                u64 ob2 = (u64)__shfl_xor((long long)b2, d, 64);
                if (ob > b) { b2 = (b > ob2) ? b : ob2; b = ob; }
                else        { b2 = (b2 > ob) ? b2 : ob; }
            }
            if (m == 0) {
                int rl = wrow * 64 + rt * 32 + (reg & 3) + 8 * (reg >> 2) + 4 * kh;
                scr[rl * 4 + wcol * 2 + 0] = b;
                scr[rl * 4 + wcol * 2 + 1] = b2;
            }
        }
    }
    __syncthreads();
    if (t < 128) {
        u64 a1 = scr[t * 4 + 0], a2 = scr[t * 4 + 1];
        u64 b1 = scr[t * 4 + 2], b2 = scr[t * 4 + 3];
        u64 top, sec;
        if (a1 > b1) { top = a1; sec = (a2 > b1) ? a2 : b1; }
        else         { top = b1; sec = (b2 > a1) ? b2 : a1; }
        u64* dst = top2 + (size_t)(row0 + t) * 16 + blockIdx.x * 2;
        dst[0] = top; dst[1] = sec;
    }
}

// ---- pass 2: global top-2 of 16 candidates, exact-fp32 rescue, gather ----
__global__ void vq_finish(const u64* __restrict__ top2, const float* __restrict__ x,
                          const float* __restrict__ emb, const float* __restrict__ cnorm,
                          float* __restrict__ outq, float* __restrict__ outi)
{
    const int t = threadIdx.x, w = t >> 6, lane = t & 63;
    const int row = blockIdx.x * 4 + w;
    u64 v = (lane < 16) ? top2[(size_t)row * 16 + lane] : 0ULL;
    u64 b = v;
    #pragma unroll
    for (int d = 1; d < 64; d <<= 1) {
        u64 o = (u64)__shfl_xor((long long)b, d, 64); b = o > b ? o : b;
    }
    u64 s = (v == b) ? 0ULL : v;
    #pragma unroll
    for (int d = 1; d < 64; d <<= 1) {
        u64 o = (u64)__shfl_xor((long long)s, d, 64); s = o > s ? o : s;
    }
    int winner = (K_EMB - 1) - (int)(unsigned int)(b & 0xffffffffULL);
    float fb = f32_unsort((unsigned int)(b >> 32));
    float fs = f32_unsort((unsigned int)(s >> 32));
    if (fb - fs <= 0.1f) {           // wave-uniform rescue (~few % of rows)
        u64 mask = __ballot((lane < 16) &&
                            (f32_unsort((unsigned int)(v >> 32)) >= fb - 0.1f));
        float4 xv = ((const float4*)(x + (size_t)row * D_DIM))[lane];
        float bestS = -3.0e38f; int bestI = 0x7fffffff;
        while (mask) {
            int bl = __ffsll((unsigned long long)mask) - 1;
            mask &= mask - 1;
            u64 cv = (u64)__shfl((long long)v, bl, 64);
            int ci = (K_EMB - 1) - (int)(unsigned int)(cv & 0xffffffffULL);
            float4 ev = ((const float4*)(emb + (size_t)ci * D_DIM))[lane];
            float d = xv.x * ev.x + xv.y * ev.y + xv.z * ev.z + xv.w * ev.w;
            #pragma unroll
            for (int dd = 1; dd < 64; dd <<= 1) d += __shfl_xor(d, dd, 64);
            float sc = d - cnorm[ci];
            if (sc > bestS || (sc == bestS && ci < bestI)) { bestS = sc; bestI = ci; }
        }
        winner = bestI;
    }
    float4 qv = ((const float4*)(emb + (size_t)winner * D_DIM))[lane];
    ((float4*)(outq + (size_t)row * D_DIM))[lane] = qv;
    if (lane == 0) outi[row] = (float)winner;
}

extern "C" void kernel_launch(void* const* d_in, const int* in_sizes, int n_in,
                              void* d_out, int out_size, void* d_ws, size_t ws_size,
                              hipStream_t stream) {
    const float* x   = (const float*)d_in[0];
    const float* emb = (const float*)d_in[1];
    float* outq = (float*)d_out;
    float* outi = outq + (size_t)N_ROWS * D_DIM;

    // x_hi/x_lo staged inside d_out (64MB of 67.37MB); consumed by vq_gemm
    // before vq_finish overwrites d_out (stream-ordered).
    _Float16* xhi = (_Float16*)d_out;
    _Float16* xlo = xhi + (size_t)N_ROWS * D_DIM;

    u64* top2 = (u64*)d_ws;                                        // 8.0 MB
    _Float16* ehi = (_Float16*)((char*)d_ws + (size_t)N_ROWS * 16 * 8);
    float* cnorm = (float*)(ehi + (size_t)K_EMB * D_DIM);          // +512 KB

    vq_prep<<<16384 + 256, 256, 0, stream>>>(x, emb, xhi, xlo, ehi, cnorm);
    vq_gemm<<<dim3(K_EMB / 128, N_ROWS / 128), 256, 0, stream>>>(xhi, xlo, ehi, cnorm, top2);
    vq_finish<<<N_ROWS / 4, 256, 0, stream>>>(top2, x, emb, cnorm, outq, outi);
}

// Round 4
// 194.979 us; speedup vs baseline: 1.5607x; 1.5607x over previous
//
#include <hip/hip_runtime.h>

// VectorQuantizer: N=65536 rows, D=256, K=1024 codes, fp32 in/out.
// argmin_k ||x-e_k||^2 == argmax_k (x.e_k - 0.5*||e_k||^2).
// Single fused main kernel. MFMA roles: A-operand = codebook (rows of C),
// B-operand = x rows (cols of C) -> each thread's acc regs all belong to one
// x row => per-thread top-3 tracking, no cross-lane reduction in the hot loop.
// x split to fp16 hi/lo in-registers (resident 128 VGPRs/thread of B-frags).
// -0.5||e||^2 injected via one extra "virtual k-step" MFMA with fp16-pair
// cnorm (exact to ~1e-4). Exact-fp32 rescue for rows with approx margin<=0.1.

#define K_EMB  1024
#define D_DIM  256
#define N_ROWS 65536

typedef unsigned int u32;
typedef unsigned long long u64;
typedef __attribute__((ext_vector_type(8)))  _Float16 f16x8;
typedef __attribute__((ext_vector_type(4)))  _Float16 f16x4;
typedef __attribute__((ext_vector_type(16))) float    f32x16;

__device__ __forceinline__ u32 f32_sortable(float f) {
    u32 u = __float_as_uint(f);
    return (u & 0x80000000u) ? ~u : (u | 0x80000000u);
}
__device__ __forceinline__ float f32_unsort(u32 u) {
    u32 v = (u & 0x80000000u) ? (u ^ 0x80000000u) : ~u;
    return __uint_as_float(v);
}

#define GLDS(gp, lp) __builtin_amdgcn_global_load_lds( \
    (const __attribute__((address_space(1))) void*)(gp), \
    (__attribute__((address_space(3))) void*)(lp), 16, 0, 0)

// ---- prep: emb fp32 -> fp16; cn2[code]={-cnh,-cnl,0..}; exact fp32 cnorm ----
__global__ void vq_prep(const float* __restrict__ emb,
                        _Float16* __restrict__ ehi,
                        _Float16* __restrict__ cn2,
                        float* __restrict__ cnormf) {
    int gid = blockIdx.x * 256 + threadIdx.x;
    int code = gid >> 6, lane = gid & 63;
    float4 v = ((const float4*)(emb + (size_t)code * D_DIM))[lane];
    f16x4 hv = {(_Float16)v.x, (_Float16)v.y, (_Float16)v.z, (_Float16)v.w};
    ((f16x4*)(ehi + (size_t)code * D_DIM))[lane] = hv;
    float s = v.x * v.x + v.y * v.y + v.z * v.z + v.w * v.w;
    #pragma unroll
    for (int off = 32; off > 0; off >>= 1) s += __shfl_down(s, off, 64);
    if (lane == 0) {
        float cn = 0.5f * s;
        cnormf[code] = cn;
        _Float16 ch = (_Float16)cn;
        _Float16 cl = (_Float16)(cn - (float)ch);
        f16x8 e = {};
        e[0] = (_Float16)(-(float)ch);
        e[1] = (_Float16)(-(float)cl);
        ((f16x8*)cn2)[code] = e;
    }
}

// ---- fused main: GEMM + top3 + rescue + gather ----
// Block: 128 x-rows (wave w -> rows [w*32, w*32+32)). Loop 16 chunks of 64
// codes. LDS A-tile layout: 16B chunk L = code + 64*kidx, kidx = 2*kstep+kh.
__global__ __launch_bounds__(256, 2) void vq_main(
    const float* __restrict__ x, const float* __restrict__ emb,
    const _Float16* __restrict__ eh, const _Float16* __restrict__ cn2,
    const float* __restrict__ cnormf,
    float* __restrict__ outq, float* __restrict__ outi)
{
    __shared__ _Float16 Ab[2048 * 8];     // 32 KB code tile
    __shared__ _Float16 Eb[64 * 8];       // 1 KB cnorm ext tile
    __shared__ int winners[128];

    const int t = threadIdx.x, w = t >> 6, lane = t & 63;
    const int m = lane & 31, kh = lane >> 5;
    const int rowbase = blockIdx.x * 128 + w * 32;
    const int myrow = rowbase + m;

    // resident B-operand frags: x[myrow], k = s*16 + kh*8 + [0..8), hi/lo fp16
    f16x8 bh[16], bl[16];
    {
        const float* xr = x + (size_t)myrow * D_DIM + kh * 8;
        #pragma unroll
        for (int s = 0; s < 16; s++) {
            float4 v0 = *(const float4*)(xr + s * 16);
            float4 v1 = *(const float4*)(xr + s * 16 + 4);
            float f[8] = {v0.x, v0.y, v0.z, v0.w, v1.x, v1.y, v1.z, v1.w};
            f16x8 h, l;
            #pragma unroll
            for (int j = 0; j < 8; j++) {
                _Float16 hh = (_Float16)f[j];
                h[j] = hh;
                l[j] = (_Float16)(f[j] - (float)hh);
            }
            bh[s] = h; bl[s] = l;
        }
    }

    // ext-step B constants: select -cnh (via xeh) and -cnl (via xel)
    f16x8 xeh = {}, xel = {};
    if (kh == 0) { xeh[0] = (_Float16)1.0f; xel[1] = (_Float16)1.0f; }

    u32 b1 = 0, b2 = 0, b3 = 0, i1 = 0, i2 = 0, i3 = 0;
    const f16x8* Af = (const f16x8*)Ab;
    const f16x8* Ef = (const f16x8*)Eb;

    for (int c = 0; c < 16; c++) {
        __syncthreads();
        #pragma unroll
        for (int i = 0; i < 8; i++) {          // wave w stages kidx = w*8+i
            int kidx = w * 8 + i;
            GLDS(eh + (size_t)(c * 64 + lane) * D_DIM + kidx * 8,
                 (_Float16*)Ab + (size_t)kidx * 64 * 8);
        }
        if (w == 0) GLDS(cn2 + (size_t)(c * 64 + lane) * 8, (_Float16*)Eb);
        __syncthreads();

        f32x16 acc0 = {}, acc1 = {};
        #pragma unroll
        for (int s = 0; s < 16; s++) {
            f16x8 a0 = Af[m      + 64 * (2 * s + kh)];
            f16x8 a1 = Af[32 + m + 64 * (2 * s + kh)];
            acc0 = __builtin_amdgcn_mfma_f32_32x32x16_f16(a0, bh[s], acc0, 0, 0, 0);
            acc0 = __builtin_amdgcn_mfma_f32_32x32x16_f16(a0, bl[s], acc0, 0, 0, 0);
            acc1 = __builtin_amdgcn_mfma_f32_32x32x16_f16(a1, bh[s], acc1, 0, 0, 0);
            acc1 = __builtin_amdgcn_mfma_f32_32x32x16_f16(a1, bl[s], acc1, 0, 0, 0);
        }
        {   // cnorm injection (kh=1 lanes read same chunk; their B side is 0)
            f16x8 e0 = Ef[m], e1 = Ef[32 + m];
            acc0 = __builtin_amdgcn_mfma_f32_32x32x16_f16(e0, xeh, acc0, 0, 0, 0);
            acc0 = __builtin_amdgcn_mfma_f32_32x32x16_f16(e0, xel, acc0, 0, 0, 0);
            acc1 = __builtin_amdgcn_mfma_f32_32x32x16_f16(e1, xeh, acc1, 0, 0, 0);
            acc1 = __builtin_amdgcn_mfma_f32_32x32x16_f16(e1, xel, acc1, 0, 0, 0);
        }

        // per-thread top3 update; per-thread code stream is ascending, so
        // strict > keeps the smallest index on exact ties.
        #pragma unroll
        for (int tt = 0; tt < 2; tt++) {
            #pragma unroll
            for (int r = 0; r < 16; r++) {
                float sc = tt ? acc1[r] : acc0[r];
                u32 code = (u32)(c * 64 + tt * 32 + (r & 3) + 8 * (r >> 2) + 4 * kh);
                u32 p = f32_sortable(sc);
                bool g1 = p > b1, g2 = p > b2, g3 = p > b3;
                u32 nb1 = g1 ? p : b1;
                u32 ni1 = g1 ? code : i1;
                u32 nb2 = g1 ? b1 : (g2 ? p : b2);
                u32 ni2 = g1 ? i1 : (g2 ? code : i2);
                u32 nb3 = g2 ? b2 : (g3 ? p : b3);
                u32 ni3 = g2 ? i2 : (g3 ? code : i3);
                b1 = nb1; b2 = nb2; b3 = nb3; i1 = ni1; i2 = ni2; i3 = ni3;
            }
        }
    }

    // merge the two kh-halves of each row (partner lane = lane ^ 32)
    #pragma unroll
    for (int q = 0; q < 3; q++) {
        u32 ps = q == 0 ? b1 : (q == 1 ? b2 : b3);
        u32 pc = q == 0 ? i1 : (q == 1 ? i2 : i3);
        ps = (u32)__shfl_xor((int)ps, 32, 64);
        pc = (u32)__shfl_xor((int)pc, 32, 64);
        bool beat1 = (ps > b1) || (ps == b1 && pc < i1);
        bool beat2 = (ps > b2) || (ps == b2 && pc < i2);
        bool beat3 = (ps > b3) || (ps == b3 && pc < i3);
        u32 nb3 = beat2 ? b2 : (beat3 ? ps : b3);
        u32 ni3 = beat2 ? i2 : (beat3 ? pc : i3);
        u32 nb2 = beat1 ? b1 : (beat2 ? ps : b2);
        u32 ni2 = beat1 ? i1 : (beat2 ? pc : i2);
        u32 nb1 = beat1 ? ps : b1;
        u32 ni1 = beat1 ? pc : i1;
        b1 = nb1; b2 = nb2; b3 = nb3; i1 = ni1; i2 = ni2; i3 = ni3;
    }

    // rescue selection (approx err worst ~0.01 << 0.1 window)
    float s1f = f32_unsort(b1), s2f = f32_unsort(b2), s3f = f32_unsort(b3);
    bool need = (s1f - s2f) <= 0.1f;
    if (kh == 0 && !need) winners[w * 32 + m] = (int)i1;
    u64 mask = __ballot(kh == 0 && need);
    while (mask) {
        int r = __ffsll((unsigned long long)mask) - 1;
        mask &= mask - 1;
        int row = rowbase + r;
        u32 c1 = (u32)__shfl((int)i1, r, 64);
        u32 c2 = (u32)__shfl((int)i2, r, 64);
        u32 c3 = (u32)__shfl((int)i3, r, 64);
        float g3 = __shfl(s1f - s3f, r, 64);
        int ncand = (g3 <= 0.1f) ? 3 : 2;
        float4 xv = ((const float4*)(x + (size_t)row * D_DIM))[lane];
        float bs = -3.0e38f; int bi = 0x7fffffff;
        u32 cand[3] = {c1, c2, c3};
        for (int q = 0; q < ncand; q++) {
            int cc = (int)cand[q];
            float4 ev = ((const float4*)(emb + (size_t)cc * D_DIM))[lane];
            float d = xv.x * ev.x + xv.y * ev.y + xv.z * ev.z + xv.w * ev.w;
            #pragma unroll
            for (int dd = 1; dd < 64; dd <<= 1) d += __shfl_xor(d, dd, 64);
            float sc = d - cnormf[cc];
            if (sc > bs || (sc == bs && cc < bi)) { bs = sc; bi = cc; }
        }
        if (lane == 0) winners[w * 32 + r] = bi;
    }

    // gather + index write (winners region is per-wave; no barrier needed)
    for (int r = 0; r < 32; r++) {
        int idx = winners[w * 32 + r];
        int row = rowbase + r;
        float4 qv = ((const float4*)(emb + (size_t)idx * D_DIM))[lane];
        ((float4*)(outq + (size_t)row * D_DIM))[lane] = qv;
    }
    if (kh == 0) outi[rowbase + m] = (float)winners[w * 32 + m];
}

extern "C" void kernel_launch(void* const* d_in, const int* in_sizes, int n_in,
                              void* d_out, int out_size, void* d_ws, size_t ws_size,
                              hipStream_t stream) {
    const float* x   = (const float*)d_in[0];
    const float* emb = (const float*)d_in[1];
    float* outq = (float*)d_out;
    float* outi = outq + (size_t)N_ROWS * D_DIM;

    _Float16* ehi = (_Float16*)d_ws;                              // 512 KB
    _Float16* cn2 = ehi + (size_t)K_EMB * D_DIM;                  // 16 KB
    float* cnormf = (float*)(cn2 + (size_t)K_EMB * 8);            // 4 KB

    vq_prep<<<K_EMB / 4, 256, 0, stream>>>(emb, ehi, cn2, cnormf);
    vq_main<<<N_ROWS / 128, 256, 0, stream>>>(x, emb, ehi, cn2, cnormf,
                                              outq, outi);
}

// Round 5
// 167.502 us; speedup vs baseline: 1.8167x; 1.1640x over previous
//
#include <hip/hip_runtime.h>

// VectorQuantizer: N=65536 rows, D=256, K=1024 codes, fp32 in/out.
// argmin_k ||x-e_k||^2 == argmax_k (x.e_k - 0.5*||e_k||^2).
// Single fused main kernel. MFMA A-operand = codebook, B-operand = x rows
// -> each thread's acc regs all belong to one x row => per-thread top-3.
// SINGLE fp16 term (x~=xh, e~=eh): |score err| <~ 0.02 worst-case; exact
// fp32 rescue for rows with approx top-2 margin <= 0.25 (also covers the
// 10-bit code-in-mantissa packing quantization <=0.03).
// Pipelined: LDS A-tile double-buffer (1 barrier/chunk, GLDS prefetch
// issued a full chunk early) + deferred top-3 (chunk c-1 processed while
// chunk c's MFMAs are in flight).

#define K_EMB  1024
#define D_DIM  256
#define N_ROWS 65536

typedef unsigned int u32;
typedef unsigned long long u64;
typedef __attribute__((ext_vector_type(8)))  _Float16 f16x8;
typedef __attribute__((ext_vector_type(4)))  _Float16 f16x4;
typedef __attribute__((ext_vector_type(16))) float    f32x16;

__device__ __forceinline__ u32 f32_sortable(float f) {
    u32 u = __float_as_uint(f);
    return u ^ ((u32)((int)u >> 31) | 0x80000000u);
}
__device__ __forceinline__ float f32_unsort(u32 u) {
    u32 v = (u & 0x80000000u) ? (u ^ 0x80000000u) : ~u;
    return __uint_as_float(v);
}

#define GLDS(gp, lp) __builtin_amdgcn_global_load_lds( \
    (const __attribute__((address_space(1))) void*)(gp), \
    (__attribute__((address_space(3))) void*)(lp), 16, 0, 0)

// ---- prep: emb fp32 -> fp16; cn2[code]={-cnh,-cnl,0..}; exact fp32 cnorm ----
__global__ void vq_prep(const float* __restrict__ emb,
                        _Float16* __restrict__ ehi,
                        _Float16* __restrict__ cn2,
                        float* __restrict__ cnormf) {
    int gid = blockIdx.x * 256 + threadIdx.x;
    int code = gid >> 6, lane = gid & 63;
    float4 v = ((const float4*)(emb + (size_t)code * D_DIM))[lane];
    f16x4 hv = {(_Float16)v.x, (_Float16)v.y, (_Float16)v.z, (_Float16)v.w};
    ((f16x4*)(ehi + (size_t)code * D_DIM))[lane] = hv;
    float s = v.x * v.x + v.y * v.y + v.z * v.z + v.w * v.w;
    #pragma unroll
    for (int off = 32; off > 0; off >>= 1) s += __shfl_down(s, off, 64);
    if (lane == 0) {
        float cn = 0.5f * s;
        cnormf[code] = cn;
        _Float16 ch = (_Float16)cn;
        _Float16 cl = (_Float16)(cn - (float)ch);
        f16x8 e = {};
        e[0] = (_Float16)(-(float)ch);
        e[1] = (_Float16)(-(float)cl);
        ((f16x8*)cn2)[code] = e;
    }
}

// ---- fused main: GEMM + top3 + rescue + gather ----
__global__ __launch_bounds__(256, 2) void vq_main(
    const float* __restrict__ x, const float* __restrict__ emb,
    const _Float16* __restrict__ eh, const _Float16* __restrict__ cn2,
    const float* __restrict__ cnormf,
    float* __restrict__ outq, float* __restrict__ outi)
{
    __shared__ _Float16 Ab[2][2048 * 8];  // double-buffered 32 KB code tiles
    __shared__ int winners[128];

    const int t = threadIdx.x, w = t >> 6, lane = t & 63;
    const int m = lane & 31, kh = lane >> 5;
    const int rowbase = blockIdx.x * 128 + w * 32;
    const int myrow = rowbase + m;
    const int kh4 = kh * 4;

    // resident B-operand frags: x[myrow] in fp16, k = s*16 + kh*8 + [0..8)
    f16x8 bh[16];
    {
        const float* xr = x + (size_t)myrow * D_DIM + kh * 8;
        #pragma unroll
        for (int s = 0; s < 16; s++) {
            float4 v0 = *(const float4*)(xr + s * 16);
            float4 v1 = *(const float4*)(xr + s * 16 + 4);
            f16x8 h = {(_Float16)v0.x, (_Float16)v0.y, (_Float16)v0.z, (_Float16)v0.w,
                       (_Float16)v1.x, (_Float16)v1.y, (_Float16)v1.z, (_Float16)v1.w};
            bh[s] = h;
        }
    }
    f16x8 xe = {};
    if (kh == 0) { xe[0] = (_Float16)1.0f; xe[1] = (_Float16)1.0f; }

    u32 b1 = 0, b2 = 0, b3 = 0;

    auto stage = [&](int c) {
        _Float16* dst = &Ab[c & 1][0];
        const _Float16* src = eh + (size_t)(c * 64 + lane) * D_DIM + w * 64;
        #pragma unroll
        for (int i = 0; i < 8; i++)
            GLDS(src + i * 8, dst + (w * 8 + i) * 512);
    };
    auto compute = [&](int buf, f32x16& a0, f32x16& a1, int c) {
        const f16x8* Af = (const f16x8*)&Ab[buf][0];
        f16x8 e0 = ((const f16x8*)cn2)[c * 64 + m];
        f16x8 e1 = ((const f16x8*)cn2)[c * 64 + 32 + m];
        a0 = (f32x16){}; a1 = (f32x16){};
        #pragma unroll
        for (int s = 0; s < 16; s++) {
            f16x8 fa0 = Af[m      + 64 * (2 * s + kh)];
            f16x8 fa1 = Af[32 + m + 64 * (2 * s + kh)];
            a0 = __builtin_amdgcn_mfma_f32_32x32x16_f16(fa0, bh[s], a0, 0, 0, 0);
            a1 = __builtin_amdgcn_mfma_f32_32x32x16_f16(fa1, bh[s], a1, 0, 0, 0);
        }
        a0 = __builtin_amdgcn_mfma_f32_32x32x16_f16(e0, xe, a0, 0, 0, 0);
        a1 = __builtin_amdgcn_mfma_f32_32x32x16_f16(e1, xe, a1, 0, 0, 0);
    };
    auto top3ins = [&](u32 p) {
        u32 t2 = b1 < p ? b1 : p;           // min(b1,p)
        u32 t3 = b2 < p ? b2 : p;           // min(b2,p)
        b1 = b1 > p ? b1 : p;
        b2 = t2 > b2 ? t2 : b2;
        b3 = t3 > b3 ? t3 : b3;
    };
    auto top3p = [&](const f32x16& a0, const f32x16& a1, int c) {
        const u32 sbase = (u32)(c * 64) + kh4;
        #pragma unroll
        for (int tt = 0; tt < 2; tt++) {
            #pragma unroll
            for (int r = 0; r < 16; r++) {
                float sc = tt ? a1[r] : a0[r];
                u32 code = sbase + tt * 32 + (r & 3) + 8 * (r >> 2);
                u32 p = (f32_sortable(sc) & 0xFFFFFC00u) | code;
                top3ins(p);
            }
        }
    };

    f32x16 accA0, accA1, accB0, accB1;
    stage(0);
    for (int cc = 0; cc < 16; cc += 2) {
        __syncthreads();
        if (cc + 1 < 16) stage(cc + 1);
        compute(0, accA0, accA1, cc);
        if (cc) top3p(accB0, accB1, cc - 1);
        __syncthreads();
        if (cc + 2 < 16) stage(cc + 2);
        compute(1, accB0, accB1, cc + 1);
        top3p(accA0, accA1, cc);
    }
    top3p(accB0, accB1, 15);

    // merge the two kh-halves of each row (partner lane = lane ^ 32)
    {
        u32 p1 = (u32)__shfl_xor((int)b1, 32, 64);
        u32 p2 = (u32)__shfl_xor((int)b2, 32, 64);
        u32 p3 = (u32)__shfl_xor((int)b3, 32, 64);
        top3ins(p1); top3ins(p2); top3ins(p3);
    }

    // rescue selection: exact fp32 re-eval when approx margin <= 0.25
    float s1f = f32_unsort(b1), s2f = f32_unsort(b2), s3f = f32_unsort(b3);
    u32 i1 = b1 & 1023u, i2 = b2 & 1023u, i3 = b3 & 1023u;
    bool need = (s1f - s2f) <= 0.25f;
    if (kh == 0 && !need) winners[w * 32 + m] = (int)i1;
    u64 mask = __ballot(kh == 0 && need);
    while (mask) {
        int r = __ffsll((unsigned long long)mask) - 1;
        mask &= mask - 1;
        int row = rowbase + r;
        u32 c1 = (u32)__shfl((int)i1, r, 64);
        u32 c2 = (u32)__shfl((int)i2, r, 64);
        u32 c3 = (u32)__shfl((int)i3, r, 64);
        float g3 = __shfl(s1f - s3f, r, 64);
        int ncand = (g3 <= 0.25f) ? 3 : 2;
        float4 xv = ((const float4*)(x + (size_t)row * D_DIM))[lane];
        float bs = -3.0e38f; int bi = 0x7fffffff;
        u32 cand[3] = {c1, c2, c3};
        for (int q = 0; q < ncand; q++) {
            int ccd = (int)cand[q];
            float4 ev = ((const float4*)(emb + (size_t)ccd * D_DIM))[lane];
            float d = xv.x * ev.x + xv.y * ev.y + xv.z * ev.z + xv.w * ev.w;
            #pragma unroll
            for (int dd = 1; dd < 64; dd <<= 1) d += __shfl_xor(d, dd, 64);
            float sc = d - cnormf[ccd];
            if (sc > bs || (sc == bs && ccd < bi)) { bs = sc; bi = ccd; }
        }
        if (lane == 0) winners[w * 32 + r] = bi;
    }

    // gather + index write (winners region is per-wave; no barrier needed)
    for (int r = 0; r < 32; r++) {
        int idx = winners[w * 32 + r];
        int row = rowbase + r;
        float4 qv = ((const float4*)(emb + (size_t)idx * D_DIM))[lane];
        ((float4*)(outq + (size_t)row * D_DIM))[lane] = qv;
    }
    if (kh == 0) outi[rowbase + m] = (float)winners[w * 32 + m];
}

extern "C" void kernel_launch(void* const* d_in, const int* in_sizes, int n_in,
                              void* d_out, int out_size, void* d_ws, size_t ws_size,
                              hipStream_t stream) {
    const float* x   = (const float*)d_in[0];
    const float* emb = (const float*)d_in[1];
    float* outq = (float*)d_out;
    float* outi = outq + (size_t)N_ROWS * D_DIM;

    _Float16* ehi = (_Float16*)d_ws;                              // 512 KB
    _Float16* cn2 = ehi + (size_t)K_EMB * D_DIM;                  // 16 KB
    float* cnormf = (float*)(cn2 + (size_t)K_EMB * 8);            // 4 KB

    vq_prep<<<K_EMB / 4, 256, 0, stream>>>(emb, ehi, cn2, cnormf);
    vq_main<<<N_ROWS / 128, 256, 0, stream>>>(x, emb, ehi, cn2, cnormf,
                                              outq, outi);
}